// Round 1
// baseline (36094.864 us; speedup 1.0000x reference)
//
#include <hip/hip_runtime.h>
#include <math.h>

#define T_SEQ 4096
#define CDIM  1024
#define NL    6
#define NH    16
#define BSZ   64
#define HDIM  64
#define MROWS 16384   // B*T

// ---------------- LayerNorm: one block per row (C=1024, 256 thr x float4) ----
__global__ __launch_bounds__(256) void ln_kernel(const float* __restrict__ x,
    const float* __restrict__ w, const float* __restrict__ bb,
    float* __restrict__ out)
{
  int row = blockIdx.x;
  int tid = threadIdx.x;
  float4 v = ((const float4*)(x + (size_t)row * CDIM))[tid];
  float s  = v.x + v.y + v.z + v.w;
  float ss = v.x*v.x + v.y*v.y + v.z*v.z + v.w*v.w;
  #pragma unroll
  for (int o = 32; o > 0; o >>= 1) { s += __shfl_down(s, o); ss += __shfl_down(ss, o); }
  __shared__ float red[8];
  int wid = tid >> 6, lane = tid & 63;
  if (lane == 0) { red[wid] = s; red[4 + wid] = ss; }
  __syncthreads();
  if (tid == 0) {
    red[0] = red[0] + red[1] + red[2] + red[3];
    red[4] = red[4] + red[5] + red[6] + red[7];
  }
  __syncthreads();
  float mean = red[0] * (1.0f / CDIM);
  float var  = red[4] * (1.0f / CDIM) - mean * mean;
  float inv  = 1.0f / sqrtf(var + 1e-5f);
  float4 w4 = ((const float4*)w)[tid];
  float4 b4 = ((const float4*)bb)[tid];
  float4 o4;
  o4.x = (v.x - mean) * inv * w4.x + b4.x;
  o4.y = (v.y - mean) * inv * w4.y + b4.y;
  o4.z = (v.z - mean) * inv * w4.z + b4.z;
  o4.w = (v.w - mean) * inv * w4.w + b4.w;
  ((float4*)(out + (size_t)row * CDIM))[tid] = o4;
}

__device__ __forceinline__ float gelu_exact(float v) {
  return 0.5f * v * (1.0f + erff(v * 0.70710678118654752440f));
}

// ---------------- fp32 GEMM: 64x64 tile, BK=16, 4x4 microtile ----------------
// EPI: 0 = +bias ; 1 = +bias+residual ; 2 = gelu(+bias) ; 3 = +bias+pos_embed
template<int EPI>
__global__ __launch_bounds__(256) void gemm_f32(const float* __restrict__ A,
    const float* __restrict__ B, const float* __restrict__ bias,
    const float* __restrict__ extra, float* __restrict__ C,
    int M, int N, int K)
{
  __shared__ float As[16][64];   // k-major
  __shared__ float Bs[16][64];
  const int tid = threadIdx.x;
  const int m0 = blockIdx.x * 64, n0 = blockIdx.y * 64;
  const int tx = tid & 15, ty = tid >> 4;
  const int ar = tid >> 2, ak = (tid & 3) * 4;      // A: row, k-quad
  const int br = tid >> 4, bc = (tid & 15) * 4;     // B: k-row, col-quad
  const float* Ap = A + (size_t)(m0 + ar) * K + ak;
  const float* Bp = B + (size_t)br * N + n0 + bc;
  float acc[4][4] = {};
  for (int k0 = 0; k0 < K; k0 += 16) {
    float4 av = *(const float4*)(Ap + k0);
    float4 bv = *(const float4*)(Bp + (size_t)k0 * N);
    __syncthreads();
    As[ak+0][ar] = av.x; As[ak+1][ar] = av.y; As[ak+2][ar] = av.z; As[ak+3][ar] = av.w;
    *(float4*)&Bs[br][bc] = bv;
    __syncthreads();
    #pragma unroll
    for (int k = 0; k < 16; ++k) {
      float4 a4 = *(const float4*)&As[k][ty * 4];
      float4 b4 = *(const float4*)&Bs[k][tx * 4];
      float avv[4] = {a4.x, a4.y, a4.z, a4.w};
      float bvv[4] = {b4.x, b4.y, b4.z, b4.w};
      #pragma unroll
      for (int i = 0; i < 4; ++i)
        #pragma unroll
        for (int j = 0; j < 4; ++j)
          acc[i][j] = fmaf(avv[i], bvv[j], acc[i][j]);
    }
  }
  float4 bi = *(const float4*)(bias + n0 + tx * 4);
  #pragma unroll
  for (int i = 0; i < 4; ++i) {
    int m = m0 + ty * 4 + i;
    size_t off = (size_t)m * N + n0 + tx * 4;
    float4 r;
    r.x = acc[i][0] + bi.x; r.y = acc[i][1] + bi.y;
    r.z = acc[i][2] + bi.z; r.w = acc[i][3] + bi.w;
    if (EPI == 1) {
      float4 rs = *(const float4*)(extra + off);
      r.x += rs.x; r.y += rs.y; r.z += rs.z; r.w += rs.w;
    } else if (EPI == 2) {
      r.x = gelu_exact(r.x); r.y = gelu_exact(r.y);
      r.z = gelu_exact(r.z); r.w = gelu_exact(r.w);
    } else if (EPI == 3) {
      size_t poff = (size_t)(m & (T_SEQ - 1)) * N + n0 + tx * 4;
      float4 p = *(const float4*)(extra + poff);
      r.x += p.x; r.y += p.y; r.z += p.z; r.w += p.w;
    }
    *(float4*)(C + off) = r;
  }
}

// ---------------- bucketed local attention -----------------------------------
// grid = (nb=64, H=16, B=4), block = 256.  qkv: [B,T,3C] fp32.
// Each block: q[64][64] x kc[128][64] -> softmax -> @ vc[128][64] -> out.
// KV LDS reused for K then V; S holds scores transposed S[j][i].
__global__ __launch_bounds__(256) void attn_kernel(const float* __restrict__ qkv,
    float* __restrict__ out)
{
  __shared__ float KV[128][64];
  __shared__ float S[128][64];
  const int n = blockIdx.x, h = blockIdx.y, b = blockIdx.z;
  const int tid = threadIdx.x;
  const int C3 = 3 * CDIM;
  const size_t bbase = (size_t)b * T_SEQ * C3;

  // stage K: rows 0..63 = previous bucket (zeros for n==0), 64..127 = current
  const int kcol = CDIM + h * HDIM;
  for (int idx = tid; idx < 128 * 16; idx += 256) {
    int j = idx >> 4, d4 = (idx & 15) << 2;
    float4 val = make_float4(0.f, 0.f, 0.f, 0.f);
    if (j >= 64) {
      int t = n * BSZ + (j - 64);
      val = *(const float4*)(qkv + bbase + (size_t)t * C3 + kcol + d4);
    } else if (n > 0) {
      int t = (n - 1) * BSZ + j;
      val = *(const float4*)(qkv + bbase + (size_t)t * C3 + kcol + d4);
    }
    *(float4*)&KV[j][d4] = val;
  }
  // q row -> registers (4 threads share a row; qc selects the 32-col chunk)
  const int qi = tid >> 2, qc = tid & 3;
  float qreg[64];
  {
    const float* qp = qkv + bbase + (size_t)(n * BSZ + qi) * C3 + h * HDIM;
    #pragma unroll
    for (int d4 = 0; d4 < 16; ++d4) {
      float4 t4 = *(const float4*)(qp + d4 * 4);
      qreg[d4*4+0] = t4.x; qreg[d4*4+1] = t4.y;
      qreg[d4*4+2] = t4.z; qreg[d4*4+3] = t4.w;
    }
  }
  __syncthreads();
  // scores for j in [qc*32, qc*32+32)
  for (int jj = 0; jj < 32; ++jj) {
    int j = qc * 32 + jj;
    float s = 0.f;
    const float4* kp = (const float4*)&KV[j][0];
    #pragma unroll
    for (int d4 = 0; d4 < 16; ++d4) {
      float4 kv = kp[d4];
      s = fmaf(qreg[d4*4+0], kv.x, s);
      s = fmaf(qreg[d4*4+1], kv.y, s);
      s = fmaf(qreg[d4*4+2], kv.z, s);
      s = fmaf(qreg[d4*4+3], kv.w, s);
    }
    s *= 0.125f;                                  // 1/sqrt(64)
    bool ok = (j < BSZ) || (j - BSZ <= qi);       // prev bucket free, cur causal
    S[j][qi] = ok ? s : -INFINITY;
  }
  // softmax over row qi (each thread owns its own 32 slots; shuffle across the 4)
  float preg[32];
  float mx = -INFINITY;
  #pragma unroll
  for (int jj = 0; jj < 32; ++jj) mx = fmaxf(mx, S[qc*32+jj][qi]);
  mx = fmaxf(mx, __shfl_xor(mx, 1));
  mx = fmaxf(mx, __shfl_xor(mx, 2));
  float l = 0.f;
  #pragma unroll
  for (int jj = 0; jj < 32; ++jj) { float p = expf(S[qc*32+jj][qi] - mx); preg[jj] = p; l += p; }
  l += __shfl_xor(l, 1);
  l += __shfl_xor(l, 2);
  float linv = 1.0f / l;
  #pragma unroll
  for (int jj = 0; jj < 32; ++jj) S[qc*32+jj][qi] = preg[jj] * linv;
  __syncthreads();            // all KV(K) reads + S writes complete
  // stage V into KV
  const int vcol = 2 * CDIM + h * HDIM;
  for (int idx = tid; idx < 128 * 16; idx += 256) {
    int j = idx >> 4, d4 = (idx & 15) << 2;
    float4 val = make_float4(0.f, 0.f, 0.f, 0.f);
    if (j >= 64) {
      int t = n * BSZ + (j - 64);
      val = *(const float4*)(qkv + bbase + (size_t)t * C3 + vcol + d4);
    } else if (n > 0) {
      int t = (n - 1) * BSZ + j;
      val = *(const float4*)(qkv + bbase + (size_t)t * C3 + vcol + d4);
    }
    *(float4*)&KV[j][d4] = val;
  }
  __syncthreads();
  // O[qi][d0..d0+15] = sum_j a[qi][j] * V[j][d]
  const int d0 = qc * 16;
  float o[16] = {};
  #pragma unroll 4
  for (int j = 0; j < 128; ++j) {
    float a = S[j][qi];
    const float4* vp = (const float4*)&KV[j][d0];
    float4 v0 = vp[0], v1 = vp[1], v2 = vp[2], v3 = vp[3];
    o[0]  = fmaf(a, v0.x, o[0]);  o[1]  = fmaf(a, v0.y, o[1]);
    o[2]  = fmaf(a, v0.z, o[2]);  o[3]  = fmaf(a, v0.w, o[3]);
    o[4]  = fmaf(a, v1.x, o[4]);  o[5]  = fmaf(a, v1.y, o[5]);
    o[6]  = fmaf(a, v1.z, o[6]);  o[7]  = fmaf(a, v1.w, o[7]);
    o[8]  = fmaf(a, v2.x, o[8]);  o[9]  = fmaf(a, v2.y, o[9]);
    o[10] = fmaf(a, v2.z, o[10]); o[11] = fmaf(a, v2.w, o[11]);
    o[12] = fmaf(a, v3.x, o[12]); o[13] = fmaf(a, v3.y, o[13]);
    o[14] = fmaf(a, v3.z, o[14]); o[15] = fmaf(a, v3.w, o[15]);
  }
  float* op = out + (size_t)(b * T_SEQ + n * BSZ + qi) * CDIM + h * HDIM + d0;
  *(float4*)(op + 0)  = make_float4(o[0],  o[1],  o[2],  o[3]);
  *(float4*)(op + 4)  = make_float4(o[4],  o[5],  o[6],  o[7]);
  *(float4*)(op + 8)  = make_float4(o[8],  o[9],  o[10], o[11]);
  *(float4*)(op + 12) = make_float4(o[12], o[13], o[14], o[15]);
}

// ---------------- critic head: one wave per row ------------------------------
__global__ __launch_bounds__(256) void critic_kernel(const float* __restrict__ x,
    const float* __restrict__ w, const float* __restrict__ b, float* __restrict__ out)
{
  int row = blockIdx.x * 4 + (threadIdx.x >> 6);
  int lane = threadIdx.x & 63;
  const float* xr = x + (size_t)row * CDIM;
  float s = 0.f;
  #pragma unroll
  for (int i = 0; i < 16; ++i) s = fmaf(xr[lane + 64*i], w[lane + 64*i], s);
  #pragma unroll
  for (int o = 32; o > 0; o >>= 1) s += __shfl_down(s, o);
  if (lane == 0) out[row] = s + b[0];
}

__global__ void copy64_kernel(const float* __restrict__ in, float* __restrict__ out)
{
  out[threadIdx.x] = in[threadIdx.x];
}

// -----------------------------------------------------------------------------
extern "C" void kernel_launch(void* const* d_in, const int* in_sizes, int n_in,
                              void* d_out, int out_size, void* d_ws, size_t ws_size,
                              hipStream_t stream)
{
  const float* states   = (const float*)d_in[0];
  const float* emb_w    = (const float*)d_in[1];
  const float* emb_b    = (const float*)d_in[2];
  const float* pos      = (const float*)d_in[3];
  const float* ln1_w    = (const float*)d_in[4];
  const float* ln1_b    = (const float*)d_in[5];
  const float* qkv_w    = (const float*)d_in[6];
  const float* qkv_b    = (const float*)d_in[7];
  const float* ow       = (const float*)d_in[8];
  const float* obs      = (const float*)d_in[9];
  const float* ln2_w    = (const float*)d_in[10];
  const float* ln2_b    = (const float*)d_in[11];
  const float* w1       = (const float*)d_in[12];
  const float* b1       = (const float*)d_in[13];
  const float* w2       = (const float*)d_in[14];
  const float* b2       = (const float*)d_in[15];
  const float* lnf_w    = (const float*)d_in[16];
  const float* lnf_b    = (const float*)d_in[17];
  const float* actor_w  = (const float*)d_in[18];
  const float* actor_b  = (const float*)d_in[19];
  const float* logstd   = (const float*)d_in[20];
  const float* critic_w = (const float*)d_in[21];
  const float* critic_b = (const float*)d_in[22];

  // ws layout (fp32): x[16384*1024] | hbuf[16384*1024] | big[16384*4096]  = 402.7 MB
  float* x    = (float*)d_ws;
  float* hbuf = x + (size_t)MROWS * CDIM;
  float* big  = hbuf + (size_t)MROWS * CDIM;

  float* logits     = (float*)d_out;                       // [16384,64]
  float* out_logstd = logits + (size_t)MROWS * 64;         // [64]
  float* out_values = out_logstd + 64;                     // [16384]

  dim3 blk(256);

  // x = states @ emb_w + emb_b + pos_embed
  gemm_f32<3><<<dim3(MROWS/64, CDIM/64), blk, 0, stream>>>(
      states, emb_w, emb_b, pos, x, MROWS, CDIM, 256);

  for (int l = 0; l < NL; ++l) {
    ln_kernel<<<MROWS, blk, 0, stream>>>(x, ln1_w + l*CDIM, ln1_b + l*CDIM, hbuf);
    gemm_f32<0><<<dim3(MROWS/64, (3*CDIM)/64), blk, 0, stream>>>(
        hbuf, qkv_w + (size_t)l*CDIM*3*CDIM, qkv_b + (size_t)l*3*CDIM, nullptr,
        big, MROWS, 3*CDIM, CDIM);
    attn_kernel<<<dim3(T_SEQ/BSZ, NH, 4), blk, 0, stream>>>(big, hbuf);
    gemm_f32<1><<<dim3(MROWS/64, CDIM/64), blk, 0, stream>>>(
        hbuf, ow + (size_t)l*CDIM*CDIM, obs + (size_t)l*CDIM, x,
        x, MROWS, CDIM, CDIM);
    ln_kernel<<<MROWS, blk, 0, stream>>>(x, ln2_w + l*CDIM, ln2_b + l*CDIM, hbuf);
    gemm_f32<2><<<dim3(MROWS/64, (4*CDIM)/64), blk, 0, stream>>>(
        hbuf, w1 + (size_t)l*CDIM*4*CDIM, b1 + (size_t)l*4*CDIM, nullptr,
        big, MROWS, 4*CDIM, CDIM);
    gemm_f32<1><<<dim3(MROWS/64, CDIM/64), blk, 0, stream>>>(
        big, w2 + (size_t)l*4*CDIM*CDIM, b2 + (size_t)l*CDIM, x,
        x, MROWS, CDIM, 4*CDIM);
  }

  ln_kernel<<<MROWS, blk, 0, stream>>>(x, lnf_w, lnf_b, hbuf);
  gemm_f32<0><<<dim3(MROWS/64, 1), blk, 0, stream>>>(
      hbuf, actor_w, actor_b, nullptr, logits, MROWS, 64, CDIM);
  critic_kernel<<<MROWS/4, blk, 0, stream>>>(hbuf, critic_w, critic_b, out_values);
  copy64_kernel<<<1, 64, 0, stream>>>(logstd, out_logstd);
}

// Round 2
// 6930.038 us; speedup vs baseline: 5.2085x; 5.2085x over previous
//
#include <hip/hip_runtime.h>
#include <math.h>
#include <stdint.h>

#define T_SEQ 4096
#define CDIM  1024
#define NL    6
#define NH    16
#define BSZ   64
#define HDIM  64
#define MROWS 16384   // B*T

typedef __bf16 bf16x8 __attribute__((ext_vector_type(8)));
typedef float  f32x4  __attribute__((ext_vector_type(4)));

__device__ __forceinline__ unsigned short f2bf(float f) {
  __bf16 h = (__bf16)f;
  return __builtin_bit_cast(unsigned short, h);
}
__device__ __forceinline__ float bf2f(unsigned short u) {
  unsigned int v = ((unsigned int)u) << 16;
  return __builtin_bit_cast(float, v);
}
__device__ __forceinline__ void unpack8(uint4 r, float* f) {
  f[0] = bf2f(r.x & 0xffff); f[1] = bf2f(r.x >> 16);
  f[2] = bf2f(r.y & 0xffff); f[3] = bf2f(r.y >> 16);
  f[4] = bf2f(r.z & 0xffff); f[5] = bf2f(r.z >> 16);
  f[6] = bf2f(r.w & 0xffff); f[7] = bf2f(r.w >> 16);
}

// async global->LDS, 16B per lane; lds dest must be wave-uniform (HW adds lane*16)
typedef __attribute__((address_space(3))) unsigned int* lds_u32p;
typedef const __attribute__((address_space(1))) unsigned int* glb_u32p;
__device__ __forceinline__ void glds16(const void* g, void* l) {
  __builtin_amdgcn_global_load_lds((glb_u32p)(uintptr_t)g, (lds_u32p)(uintptr_t)l, 16, 0, 0);
}

__device__ __forceinline__ float gelu_exact(float v) {
  return 0.5f * v * (1.0f + erff(v * 0.70710678118654752440f));
}

// ---------------- LayerNorm: one block per row; OBF=1 -> bf16 out ------------
template<int OBF>
__global__ __launch_bounds__(256) void ln_kernel(const float* __restrict__ x,
    const float* __restrict__ w, const float* __restrict__ bb, void* __restrict__ out)
{
  int row = blockIdx.x;
  int tid = threadIdx.x;
  float4 v = ((const float4*)(x + (size_t)row * CDIM))[tid];
  float s  = v.x + v.y + v.z + v.w;
  float ss = v.x*v.x + v.y*v.y + v.z*v.z + v.w*v.w;
  #pragma unroll
  for (int o = 32; o > 0; o >>= 1) { s += __shfl_down(s, o); ss += __shfl_down(ss, o); }
  __shared__ float red[8];
  int wid = tid >> 6, lane = tid & 63;
  if (lane == 0) { red[wid] = s; red[4 + wid] = ss; }
  __syncthreads();
  if (tid == 0) {
    red[0] = red[0] + red[1] + red[2] + red[3];
    red[4] = red[4] + red[5] + red[6] + red[7];
  }
  __syncthreads();
  float mean = red[0] * (1.0f / CDIM);
  float var  = red[4] * (1.0f / CDIM) - mean * mean;
  float inv  = 1.0f / sqrtf(var + 1e-5f);
  float4 w4 = ((const float4*)w)[tid];
  float4 b4 = ((const float4*)bb)[tid];
  float4 o4;
  o4.x = (v.x - mean) * inv * w4.x + b4.x;
  o4.y = (v.y - mean) * inv * w4.y + b4.y;
  o4.z = (v.z - mean) * inv * w4.z + b4.z;
  o4.w = (v.w - mean) * inv * w4.w + b4.w;
  if (OBF) {
    ushort4 o;
    o.x = f2bf(o4.x); o.y = f2bf(o4.y); o.z = f2bf(o4.z); o.w = f2bf(o4.w);
    ((ushort4*)((unsigned short*)out + (size_t)row * CDIM))[tid] = o;
  } else {
    ((float4*)((float*)out + (size_t)row * CDIM))[tid] = o4;
  }
}

// ---------------- weight fp32 [K,N] -> bf16 W^T [N,K] ------------------------
__global__ __launch_bounds__(256) void convT(const float* __restrict__ W,
    unsigned short* __restrict__ Wt, int K, int N)
{
  __shared__ float tile[32][33];
  const int kt = blockIdx.y * 32, nt = blockIdx.x * 32;
  const int r = threadIdx.x >> 3;        // 0..31
  const int c = (threadIdx.x & 7) * 4;   // 0..28
  float4 v = *(const float4*)(W + (size_t)(kt + r) * N + nt + c);
  tile[r][c] = v.x; tile[r][c+1] = v.y; tile[r][c+2] = v.z; tile[r][c+3] = v.w;
  __syncthreads();
  ushort4 o;
  o.x = f2bf(tile[c+0][r]); o.y = f2bf(tile[c+1][r]);
  o.z = f2bf(tile[c+2][r]); o.w = f2bf(tile[c+3][r]);
  *(ushort4*)(Wt + (size_t)(nt + r) * K + kt + c) = o;
}

// ---------------- flat fp32 -> bf16 ------------------------------------------
__global__ void conv_flat(const float* __restrict__ in, unsigned short* __restrict__ out)
{
  int i = blockIdx.x * blockDim.x + threadIdx.x;
  float4 v = ((const float4*)in)[i];
  ushort4 o;
  o.x = f2bf(v.x); o.y = f2bf(v.y); o.z = f2bf(v.z); o.w = f2bf(v.w);
  ((ushort4*)out)[i] = o;
}

// ---------------- bf16 MFMA GEMM: C = A[M,K] @ B^T[N,K]^T --------------------
// 128x128 tile, BK=32, 4 waves each 64x64 (4x4 frags of 16x16x32).
// EPI: 0=+bias ; 1=+bias+residual(extra f32) ; 2=gelu(+bias) ; 3=+bias+pos(extra)
// OBF: 1 -> bf16 output, 0 -> fp32 output.
template<int EPI, int OBF>
__global__ __launch_bounds__(256) void gemm_bf16(
    const unsigned short* __restrict__ A, const unsigned short* __restrict__ Bt,
    const float* __restrict__ bias, const float* __restrict__ extra,
    void* __restrict__ Cout, int M, int N, int K)
{
  __shared__ __align__(16) unsigned short As[128 * 32];  // [row][k] 64B rows
  __shared__ __align__(16) unsigned short Bs[128 * 32];  // [n][k]
  const int tid = threadIdx.x;
  const int wave = tid >> 6, lane = tid & 63;
  const int m0 = blockIdx.x * 128, n0 = blockIdx.y * 128;
  const int wm = (wave & 1) * 64, wn = (wave >> 1) * 64;

  // staging: each wave fills 32 A-rows and 32 B-rows via 2+2 glds16
  const int srow = wave * 32 + (lane >> 2);       // +0 / +16
  const int skq  = (lane & 3) * 8;                // element offset in k
  const unsigned short* ag0 = A  + (size_t)(m0 + srow) * K + skq;
  const unsigned short* ag1 = ag0 + (size_t)16 * K;
  const unsigned short* bg0 = Bt + (size_t)(n0 + srow) * K + skq;
  const unsigned short* bg1 = bg0 + (size_t)16 * K;
  char* al0 = (char*)As + (wave * 32) * 64;
  char* al1 = al0 + 16 * 64;
  char* bl0 = (char*)Bs + (wave * 32) * 64;
  char* bl1 = bl0 + 16 * 64;

  // fragment read offsets (bytes)
  const int fra = (wm + (lane & 15)) * 64 + (lane >> 4) * 16;
  const int frb = (wn + (lane & 15)) * 64 + (lane >> 4) * 16;

  f32x4 acc[4][4];
  #pragma unroll
  for (int i = 0; i < 4; ++i)
    #pragma unroll
    for (int j = 0; j < 4; ++j) acc[i][j] = (f32x4){0.f, 0.f, 0.f, 0.f};

  for (int k0 = 0; k0 < K; k0 += 32) {
    __syncthreads();                   // LDS consumed before overwrite
    glds16(ag0 + k0, al0);
    glds16(ag1 + k0, al1);
    glds16(bg0 + k0, bl0);
    glds16(bg1 + k0, bl1);
    __syncthreads();                   // drains vmcnt before barrier release
    bf16x8 af[4], bf[4];
    #pragma unroll
    for (int i = 0; i < 4; ++i) af[i] = *(const bf16x8*)((const char*)As + fra + i * 1024);
    #pragma unroll
    for (int j = 0; j < 4; ++j) bf[j] = *(const bf16x8*)((const char*)Bs + frb + j * 1024);
    #pragma unroll
    for (int i = 0; i < 4; ++i)
      #pragma unroll
      for (int j = 0; j < 4; ++j)
        acc[i][j] = __builtin_amdgcn_mfma_f32_16x16x32_bf16(af[i], bf[j], acc[i][j], 0, 0, 0);
  }

  // epilogue: C/D layout col=lane&15, row=(lane>>4)*4+reg
  const int cl = lane & 15, rq = (lane >> 4) * 4;
  #pragma unroll
  for (int j = 0; j < 4; ++j) {
    const int n = n0 + wn + j * 16 + cl;
    const float bj = bias[n];
    #pragma unroll
    for (int i = 0; i < 4; ++i) {
      const int mb = m0 + wm + i * 16 + rq;
      #pragma unroll
      for (int r = 0; r < 4; ++r) {
        const int m = mb + r;
        const size_t off = (size_t)m * N + n;
        float val = acc[i][j][r] + bj;
        if (EPI == 1) val += extra[off];
        else if (EPI == 2) val = gelu_exact(val);
        else if (EPI == 3) val += extra[(size_t)(m & (T_SEQ - 1)) * N + n];
        if (OBF) ((unsigned short*)Cout)[off] = f2bf(val);
        else     ((float*)Cout)[off] = val;
      }
    }
  }
}

// ---------------- fp32 GEMM (kept for tiny actor head) -----------------------
template<int EPI>
__global__ __launch_bounds__(256) void gemm_f32(const float* __restrict__ A,
    const float* __restrict__ B, const float* __restrict__ bias,
    const float* __restrict__ extra, float* __restrict__ C,
    int M, int N, int K)
{
  __shared__ float As[16][64];
  __shared__ float Bs[16][64];
  const int tid = threadIdx.x;
  const int m0 = blockIdx.x * 64, n0 = blockIdx.y * 64;
  const int tx = tid & 15, ty = tid >> 4;
  const int ar = tid >> 2, ak = (tid & 3) * 4;
  const int br = tid >> 4, bc = (tid & 15) * 4;
  const float* Ap = A + (size_t)(m0 + ar) * K + ak;
  const float* Bp = B + (size_t)br * N + n0 + bc;
  float acc[4][4] = {};
  for (int k0 = 0; k0 < K; k0 += 16) {
    float4 av = *(const float4*)(Ap + k0);
    float4 bv = *(const float4*)(Bp + (size_t)k0 * N);
    __syncthreads();
    As[ak+0][ar] = av.x; As[ak+1][ar] = av.y; As[ak+2][ar] = av.z; As[ak+3][ar] = av.w;
    *(float4*)&Bs[br][bc] = bv;
    __syncthreads();
    #pragma unroll
    for (int k = 0; k < 16; ++k) {
      float4 a4 = *(const float4*)&As[k][ty * 4];
      float4 b4 = *(const float4*)&Bs[k][tx * 4];
      float avv[4] = {a4.x, a4.y, a4.z, a4.w};
      float bvv[4] = {b4.x, b4.y, b4.z, b4.w};
      #pragma unroll
      for (int i = 0; i < 4; ++i)
        #pragma unroll
        for (int j = 0; j < 4; ++j)
          acc[i][j] = fmaf(avv[i], bvv[j], acc[i][j]);
    }
  }
  float4 bi = *(const float4*)(bias + n0 + tx * 4);
  #pragma unroll
  for (int i = 0; i < 4; ++i) {
    int m = m0 + ty * 4 + i;
    size_t off = (size_t)m * N + n0 + tx * 4;
    float4 r;
    r.x = acc[i][0] + bi.x; r.y = acc[i][1] + bi.y;
    r.z = acc[i][2] + bi.z; r.w = acc[i][3] + bi.w;
    if (EPI == 1) {
      float4 rs = *(const float4*)(extra + off);
      r.x += rs.x; r.y += rs.y; r.z += rs.z; r.w += rs.w;
    }
    *(float4*)(C + off) = r;
  }
}

// ---------------- bucketed local attention (bf16 qkv in, bf16 out) -----------
__global__ __launch_bounds__(256) void attn_kernel(const unsigned short* __restrict__ qkv,
    unsigned short* __restrict__ out)
{
  __shared__ float KV[128][64];
  __shared__ float S[128][64];
  const int n = blockIdx.x, h = blockIdx.y, b = blockIdx.z;
  const int tid = threadIdx.x;
  const int C3 = 3 * CDIM;
  const size_t bbase = (size_t)b * T_SEQ * C3;

  // stage K (rows 0..63 = prev bucket, zeros if n==0; 64..127 = cur)
  const int kcol = CDIM + h * HDIM;
  for (int idx = tid; idx < 128 * 8; idx += 256) {
    int j = idx >> 3, d8 = (idx & 7) * 8;
    float f[8] = {0.f,0.f,0.f,0.f,0.f,0.f,0.f,0.f};
    if (j >= 64 || n > 0) {
      int t = (j >= 64) ? (n * BSZ + (j - 64)) : ((n - 1) * BSZ + j);
      uint4 r = *(const uint4*)(qkv + bbase + (size_t)t * C3 + kcol + d8);
      unpack8(r, f);
    }
    #pragma unroll
    for (int u = 0; u < 8; ++u) KV[j][d8 + u] = f[u];
  }
  const int qi = tid >> 2, qc = tid & 3;
  float qreg[64];
  {
    const unsigned short* qp = qkv + bbase + (size_t)(n * BSZ + qi) * C3 + h * HDIM;
    #pragma unroll
    for (int d8 = 0; d8 < 8; ++d8) {
      uint4 r = *(const uint4*)(qp + d8 * 8);
      unpack8(r, qreg + d8 * 8);
    }
  }
  __syncthreads();
  for (int jj = 0; jj < 32; ++jj) {
    int j = qc * 32 + jj;
    float s = 0.f;
    const float4* kp = (const float4*)&KV[j][0];
    #pragma unroll
    for (int d4 = 0; d4 < 16; ++d4) {
      float4 kv = kp[d4];
      s = fmaf(qreg[d4*4+0], kv.x, s);
      s = fmaf(qreg[d4*4+1], kv.y, s);
      s = fmaf(qreg[d4*4+2], kv.z, s);
      s = fmaf(qreg[d4*4+3], kv.w, s);
    }
    s *= 0.125f;
    bool ok = (j < BSZ) || (j - BSZ <= qi);
    S[j][qi] = ok ? s : -INFINITY;
  }
  float preg[32];
  float mx = -INFINITY;
  #pragma unroll
  for (int jj = 0; jj < 32; ++jj) mx = fmaxf(mx, S[qc*32+jj][qi]);
  mx = fmaxf(mx, __shfl_xor(mx, 1));
  mx = fmaxf(mx, __shfl_xor(mx, 2));
  float l = 0.f;
  #pragma unroll
  for (int jj = 0; jj < 32; ++jj) { float p = expf(S[qc*32+jj][qi] - mx); preg[jj] = p; l += p; }
  l += __shfl_xor(l, 1);
  l += __shfl_xor(l, 2);
  float linv = 1.0f / l;
  #pragma unroll
  for (int jj = 0; jj < 32; ++jj) S[qc*32+jj][qi] = preg[jj] * linv;
  __syncthreads();
  // stage V
  const int vcol = 2 * CDIM + h * HDIM;
  for (int idx = tid; idx < 128 * 8; idx += 256) {
    int j = idx >> 3, d8 = (idx & 7) * 8;
    float f[8] = {0.f,0.f,0.f,0.f,0.f,0.f,0.f,0.f};
    if (j >= 64 || n > 0) {
      int t = (j >= 64) ? (n * BSZ + (j - 64)) : ((n - 1) * BSZ + j);
      uint4 r = *(const uint4*)(qkv + bbase + (size_t)t * C3 + vcol + d8);
      unpack8(r, f);
    }
    #pragma unroll
    for (int u = 0; u < 8; ++u) KV[j][d8 + u] = f[u];
  }
  __syncthreads();
  const int d0 = qc * 16;
  float o[16] = {};
  #pragma unroll 4
  for (int j = 0; j < 128; ++j) {
    float a = S[j][qi];
    const float4* vp = (const float4*)&KV[j][d0];
    float4 v0 = vp[0], v1 = vp[1], v2 = vp[2], v3 = vp[3];
    o[0]  = fmaf(a, v0.x, o[0]);  o[1]  = fmaf(a, v0.y, o[1]);
    o[2]  = fmaf(a, v0.z, o[2]);  o[3]  = fmaf(a, v0.w, o[3]);
    o[4]  = fmaf(a, v1.x, o[4]);  o[5]  = fmaf(a, v1.y, o[5]);
    o[6]  = fmaf(a, v1.z, o[6]);  o[7]  = fmaf(a, v1.w, o[7]);
    o[8]  = fmaf(a, v2.x, o[8]);  o[9]  = fmaf(a, v2.y, o[9]);
    o[10] = fmaf(a, v2.z, o[10]); o[11] = fmaf(a, v2.w, o[11]);
    o[12] = fmaf(a, v3.x, o[12]); o[13] = fmaf(a, v3.y, o[13]);
    o[14] = fmaf(a, v3.z, o[14]); o[15] = fmaf(a, v3.w, o[15]);
  }
  unsigned short* op = out + (size_t)(b * T_SEQ + n * BSZ + qi) * CDIM + h * HDIM + d0;
  #pragma unroll
  for (int c = 0; c < 4; ++c) {
    ushort4 pk;
    pk.x = f2bf(o[c*4+0]); pk.y = f2bf(o[c*4+1]);
    pk.z = f2bf(o[c*4+2]); pk.w = f2bf(o[c*4+3]);
    *(ushort4*)(op + c * 4) = pk;
  }
}

// ---------------- critic head ------------------------------------------------
__global__ __launch_bounds__(256) void critic_kernel(const float* __restrict__ x,
    const float* __restrict__ w, const float* __restrict__ b, float* __restrict__ out)
{
  int row = blockIdx.x * 4 + (threadIdx.x >> 6);
  int lane = threadIdx.x & 63;
  const float* xr = x + (size_t)row * CDIM;
  float s = 0.f;
  #pragma unroll
  for (int i = 0; i < 16; ++i) s = fmaf(xr[lane + 64*i], w[lane + 64*i], s);
  #pragma unroll
  for (int o = 32; o > 0; o >>= 1) s += __shfl_down(s, o);
  if (lane == 0) out[row] = s + b[0];
}

__global__ void copy64_kernel(const float* __restrict__ in, float* __restrict__ out)
{
  out[threadIdx.x] = in[threadIdx.x];
}

// -----------------------------------------------------------------------------
extern "C" void kernel_launch(void* const* d_in, const int* in_sizes, int n_in,
                              void* d_out, int out_size, void* d_ws, size_t ws_size,
                              hipStream_t stream)
{
  const float* states   = (const float*)d_in[0];
  const float* emb_w    = (const float*)d_in[1];
  const float* emb_b    = (const float*)d_in[2];
  const float* pos      = (const float*)d_in[3];
  const float* ln1_w    = (const float*)d_in[4];
  const float* ln1_b    = (const float*)d_in[5];
  const float* qkv_w    = (const float*)d_in[6];
  const float* qkv_b    = (const float*)d_in[7];
  const float* ow       = (const float*)d_in[8];
  const float* obs      = (const float*)d_in[9];
  const float* ln2_w    = (const float*)d_in[10];
  const float* ln2_b    = (const float*)d_in[11];
  const float* w1       = (const float*)d_in[12];
  const float* b1       = (const float*)d_in[13];
  const float* w2       = (const float*)d_in[14];
  const float* b2       = (const float*)d_in[15];
  const float* lnf_w    = (const float*)d_in[16];
  const float* lnf_b    = (const float*)d_in[17];
  const float* actor_w  = (const float*)d_in[18];
  const float* actor_b  = (const float*)d_in[19];
  const float* logstd   = (const float*)d_in[20];
  const float* critic_w = (const float*)d_in[21];
  const float* critic_b = (const float*)d_in[22];

  // ws layout (bytes):
  //   [0,64M)    x fp32 residual
  //   [64M,160M) qkvb bf16 [16384,3072]   (aliased as hbuf fp32 after the loop)
  //   [160M,192M) lnb bf16 [16384,1024]   (ln out / attn out)
  //   [192M,320M) mlpb bf16 [16384,4096]  (aliased as statesb bf16 pre-loop)
  //   [320M,~345M) per-layer bf16 W^T: wq|wo|wm1|wm2|wemb
  char* wsb = (char*)d_ws;
  float* x              = (float*)wsb;
  unsigned short* qkvb  = (unsigned short*)(wsb + (64ull  << 20));
  float* hbuf           = (float*)(wsb + (64ull << 20));
  unsigned short* lnb   = (unsigned short*)(wsb + (160ull << 20));
  unsigned short* mlpb  = (unsigned short*)(wsb + (192ull << 20));
  unsigned short* statesb = mlpb;
  unsigned short* wq    = (unsigned short*)(wsb + (320ull << 20));
  unsigned short* wo    = wq  + (size_t)3072 * 1024;
  unsigned short* wm1   = wo  + (size_t)1024 * 1024;
  unsigned short* wm2   = wm1 + (size_t)4096 * 1024;
  unsigned short* wemb  = wm2 + (size_t)1024 * 4096;

  float* logits     = (float*)d_out;
  float* out_logstd = logits + (size_t)MROWS * 64;
  float* out_values = out_logstd + 64;

  dim3 blk(256);

  // embed: x = states@emb_w + emb_b + pos
  conv_flat<<<4096, blk, 0, stream>>>(states, statesb);               // 16384*256
  convT<<<dim3(1024/32, 256/32), blk, 0, stream>>>(emb_w, wemb, 256, 1024);
  gemm_bf16<3,0><<<dim3(128, 8), blk, 0, stream>>>(
      statesb, wemb, emb_b, pos, x, MROWS, CDIM, 256);

  for (int l = 0; l < NL; ++l) {
    convT<<<dim3(3072/32, 1024/32), blk, 0, stream>>>(qkv_w + (size_t)l*CDIM*3*CDIM, wq,  1024, 3072);
    convT<<<dim3(1024/32, 1024/32), blk, 0, stream>>>(ow    + (size_t)l*CDIM*CDIM,   wo,  1024, 1024);
    convT<<<dim3(4096/32, 1024/32), blk, 0, stream>>>(w1    + (size_t)l*CDIM*4*CDIM, wm1, 1024, 4096);
    convT<<<dim3(1024/32, 4096/32), blk, 0, stream>>>(w2    + (size_t)l*4*CDIM*CDIM, wm2, 4096, 1024);

    ln_kernel<1><<<MROWS, blk, 0, stream>>>(x, ln1_w + l*CDIM, ln1_b + l*CDIM, lnb);
    gemm_bf16<0,1><<<dim3(128, 24), blk, 0, stream>>>(
        lnb, wq, qkv_b + (size_t)l*3*CDIM, nullptr, qkvb, MROWS, 3*CDIM, CDIM);
    attn_kernel<<<dim3(T_SEQ/BSZ, NH, 4), blk, 0, stream>>>(qkvb, lnb);
    gemm_bf16<1,0><<<dim3(128, 8), blk, 0, stream>>>(
        lnb, wo, obs + (size_t)l*CDIM, x, x, MROWS, CDIM, CDIM);
    ln_kernel<1><<<MROWS, blk, 0, stream>>>(x, ln2_w + l*CDIM, ln2_b + l*CDIM, lnb);
    gemm_bf16<2,1><<<dim3(128, 32), blk, 0, stream>>>(
        lnb, wm1, b1 + (size_t)l*4*CDIM, nullptr, mlpb, MROWS, 4*CDIM, CDIM);
    gemm_bf16<1,0><<<dim3(128, 8), blk, 0, stream>>>(
        mlpb, wm2, b2 + (size_t)l*CDIM, x, x, MROWS, CDIM, 4*CDIM);
  }

  ln_kernel<0><<<MROWS, blk, 0, stream>>>(x, lnf_w, lnf_b, hbuf);
  gemm_f32<0><<<dim3(MROWS/64, 1), blk, 0, stream>>>(
      hbuf, actor_w, actor_b, nullptr, logits, MROWS, 64, CDIM);
  critic_kernel<<<MROWS/4, blk, 0, stream>>>(hbuf, critic_w, critic_b, out_values);
  copy64_kernel<<<1, 64, 0, stream>>>(logstd, out_logstd);
}

// Round 3
// 5010.130 us; speedup vs baseline: 7.2044x; 1.3832x over previous
//
#include <hip/hip_runtime.h>
#include <math.h>
#include <stdint.h>

#define T_SEQ 4096
#define CDIM  1024
#define NL    6
#define NH    16
#define BSZ   64
#define HDIM  64
#define MROWS 16384   // B*T

typedef __bf16 bf16x8 __attribute__((ext_vector_type(8)));
typedef float  f32x4  __attribute__((ext_vector_type(4)));

__device__ __forceinline__ unsigned short f2bf(float f) {
  __bf16 h = (__bf16)f;
  return __builtin_bit_cast(unsigned short, h);
}
__device__ __forceinline__ float bf2f(unsigned short u) {
  unsigned int v = ((unsigned int)u) << 16;
  return __builtin_bit_cast(float, v);
}

// async global->LDS, 16B per lane; lds dest must be wave-uniform (HW adds lane*16)
typedef __attribute__((address_space(3))) unsigned int* lds_u32p;
typedef const __attribute__((address_space(1))) unsigned int* glb_u32p;
__device__ __forceinline__ void glds16(const void* g, void* l) {
  __builtin_amdgcn_global_load_lds((glb_u32p)(uintptr_t)g, (lds_u32p)(uintptr_t)l, 16, 0, 0);
}

__device__ __forceinline__ float gelu_exact(float v) {
  return 0.5f * v * (1.0f + erff(v * 0.70710678118654752440f));
}

// ---------------- LayerNorm: one block per row; OBF=1 -> bf16 out ------------
template<int OBF>
__global__ __launch_bounds__(256) void ln_kernel(const float* __restrict__ x,
    const float* __restrict__ w, const float* __restrict__ bb, void* __restrict__ out)
{
  int row = blockIdx.x;
  int tid = threadIdx.x;
  float4 v = ((const float4*)(x + (size_t)row * CDIM))[tid];
  float s  = v.x + v.y + v.z + v.w;
  float ss = v.x*v.x + v.y*v.y + v.z*v.z + v.w*v.w;
  #pragma unroll
  for (int o = 32; o > 0; o >>= 1) { s += __shfl_down(s, o); ss += __shfl_down(ss, o); }
  __shared__ float red[8];
  int wid = tid >> 6, lane = tid & 63;
  if (lane == 0) { red[wid] = s; red[4 + wid] = ss; }
  __syncthreads();
  if (tid == 0) {
    red[0] = red[0] + red[1] + red[2] + red[3];
    red[4] = red[4] + red[5] + red[6] + red[7];
  }
  __syncthreads();
  float mean = red[0] * (1.0f / CDIM);
  float var  = red[4] * (1.0f / CDIM) - mean * mean;
  float inv  = 1.0f / sqrtf(var + 1e-5f);
  float4 w4 = ((const float4*)w)[tid];
  float4 b4 = ((const float4*)bb)[tid];
  float4 o4;
  o4.x = (v.x - mean) * inv * w4.x + b4.x;
  o4.y = (v.y - mean) * inv * w4.y + b4.y;
  o4.z = (v.z - mean) * inv * w4.z + b4.z;
  o4.w = (v.w - mean) * inv * w4.w + b4.w;
  if (OBF) {
    ushort4 o;
    o.x = f2bf(o4.x); o.y = f2bf(o4.y); o.z = f2bf(o4.z); o.w = f2bf(o4.w);
    ((ushort4*)((unsigned short*)out + (size_t)row * CDIM))[tid] = o;
  } else {
    ((float4*)((float*)out + (size_t)row * CDIM))[tid] = o4;
  }
}

// ---------------- weight fp32 [K,N] -> bf16 W^T [N,K] ------------------------
__global__ __launch_bounds__(256) void convT(const float* __restrict__ W,
    unsigned short* __restrict__ Wt, int K, int N)
{
  __shared__ float tile[32][33];
  const int kt = blockIdx.y * 32, nt = blockIdx.x * 32;
  const int r = threadIdx.x >> 3;        // 0..31
  const int c = (threadIdx.x & 7) * 4;   // 0..28
  float4 v = *(const float4*)(W + (size_t)(kt + r) * N + nt + c);
  tile[r][c] = v.x; tile[r][c+1] = v.y; tile[r][c+2] = v.z; tile[r][c+3] = v.w;
  __syncthreads();
  ushort4 o;
  o.x = f2bf(tile[c+0][r]); o.y = f2bf(tile[c+1][r]);
  o.z = f2bf(tile[c+2][r]); o.w = f2bf(tile[c+3][r]);
  *(ushort4*)(Wt + (size_t)(nt + r) * K + kt + c) = o;
}

// ---------------- flat fp32 -> bf16 ------------------------------------------
__global__ void conv_flat(const float* __restrict__ in, unsigned short* __restrict__ out)
{
  int i = blockIdx.x * blockDim.x + threadIdx.x;
  float4 v = ((const float4*)in)[i];
  ushort4 o;
  o.x = f2bf(v.x); o.y = f2bf(v.y); o.z = f2bf(v.z); o.w = f2bf(v.w);
  ((ushort4*)out)[i] = o;
}

// ---------------- bf16 MFMA GEMM: C = A[M,K] @ B^T[N,K]^T --------------------
// 1D grid with 8-M-tile group swizzle for A reuse in L2/L3.
// EPI: 0=+bias ; 1=+bias+residual(extra f32) ; 2=gelu(+bias) ; 3=+bias+pos(extra)
template<int EPI, int OBF>
__global__ __launch_bounds__(256) void gemm_bf16(
    const unsigned short* __restrict__ A, const unsigned short* __restrict__ Bt,
    const float* __restrict__ bias, const float* __restrict__ extra,
    void* __restrict__ Cout, int M, int N, int K)
{
  __shared__ __align__(16) unsigned short As[128 * 32];  // [row][k] 64B rows
  __shared__ __align__(16) unsigned short Bs[128 * 32];  // [n][k]
  const int tid = threadIdx.x;
  const int wave = tid >> 6, lane = tid & 63;
  // swizzle: groups of 8 m-tiles sweep all n-tiles (A read ~once from HBM)
  const int ntiles = N >> 7;
  const int per = ntiles << 3;
  const int g = blockIdx.x / per, rr = blockIdx.x % per;
  const int m0 = ((g << 3) + (rr & 7)) << 7;
  const int n0 = (rr >> 3) << 7;
  const int wm = (wave & 1) * 64, wn = (wave >> 1) * 64;

  const int srow = wave * 32 + (lane >> 2);
  const int skq  = (lane & 3) * 8;
  const unsigned short* ag0 = A  + (size_t)(m0 + srow) * K + skq;
  const unsigned short* ag1 = ag0 + (size_t)16 * K;
  const unsigned short* bg0 = Bt + (size_t)(n0 + srow) * K + skq;
  const unsigned short* bg1 = bg0 + (size_t)16 * K;
  char* al0 = (char*)As + (wave * 32) * 64;
  char* al1 = al0 + 16 * 64;
  char* bl0 = (char*)Bs + (wave * 32) * 64;
  char* bl1 = bl0 + 16 * 64;

  const int fra = (wm + (lane & 15)) * 64 + (lane >> 4) * 16;
  const int frb = (wn + (lane & 15)) * 64 + (lane >> 4) * 16;

  f32x4 acc[4][4];
  #pragma unroll
  for (int i = 0; i < 4; ++i)
    #pragma unroll
    for (int j = 0; j < 4; ++j) acc[i][j] = (f32x4){0.f, 0.f, 0.f, 0.f};

  for (int k0 = 0; k0 < K; k0 += 32) {
    __syncthreads();
    glds16(ag0 + k0, al0);
    glds16(ag1 + k0, al1);
    glds16(bg0 + k0, bl0);
    glds16(bg1 + k0, bl1);
    __syncthreads();
    bf16x8 af[4], bfr[4];
    #pragma unroll
    for (int i = 0; i < 4; ++i) af[i] = *(const bf16x8*)((const char*)As + fra + i * 1024);
    #pragma unroll
    for (int j = 0; j < 4; ++j) bfr[j] = *(const bf16x8*)((const char*)Bs + frb + j * 1024);
    #pragma unroll
    for (int i = 0; i < 4; ++i)
      #pragma unroll
      for (int j = 0; j < 4; ++j)
        acc[i][j] = __builtin_amdgcn_mfma_f32_16x16x32_bf16(af[i], bfr[j], acc[i][j], 0, 0, 0);
  }

  const int cl = lane & 15, rq = (lane >> 4) * 4;
  #pragma unroll
  for (int j = 0; j < 4; ++j) {
    const int n = n0 + wn + j * 16 + cl;
    const float bj = bias[n];
    #pragma unroll
    for (int i = 0; i < 4; ++i) {
      const int mb = m0 + wm + i * 16 + rq;
      #pragma unroll
      for (int r = 0; r < 4; ++r) {
        const int m = mb + r;
        const size_t off = (size_t)m * N + n;
        float val = acc[i][j][r] + bj;
        if (EPI == 1) val += extra[off];
        else if (EPI == 2) val = gelu_exact(val);
        else if (EPI == 3) val += extra[(size_t)(m & (T_SEQ - 1)) * N + n];
        if (OBF) ((unsigned short*)Cout)[off] = f2bf(val);
        else     ((float*)Cout)[off] = val;
      }
    }
  }
}

// ---------------- fp32 GEMM (kept for tiny actor head) -----------------------
template<int EPI>
__global__ __launch_bounds__(256) void gemm_f32(const float* __restrict__ A,
    const float* __restrict__ B, const float* __restrict__ bias,
    const float* __restrict__ extra, float* __restrict__ C,
    int M, int N, int K)
{
  __shared__ float As[16][64];
  __shared__ float Bs[16][64];
  const int tid = threadIdx.x;
  const int m0 = blockIdx.x * 64, n0 = blockIdx.y * 64;
  const int tx = tid & 15, ty = tid >> 4;
  const int ar = tid >> 2, ak = (tid & 3) * 4;
  const int br = tid >> 4, bc = (tid & 15) * 4;
  const float* Ap = A + (size_t)(m0 + ar) * K + ak;
  const float* Bp = B + (size_t)br * N + n0 + bc;
  float acc[4][4] = {};
  for (int k0 = 0; k0 < K; k0 += 16) {
    float4 av = *(const float4*)(Ap + k0);
    float4 bv = *(const float4*)(Bp + (size_t)k0 * N);
    __syncthreads();
    As[ak+0][ar] = av.x; As[ak+1][ar] = av.y; As[ak+2][ar] = av.z; As[ak+3][ar] = av.w;
    *(float4*)&Bs[br][bc] = bv;
    __syncthreads();
    #pragma unroll
    for (int k = 0; k < 16; ++k) {
      float4 a4 = *(const float4*)&As[k][ty * 4];
      float4 b4 = *(const float4*)&Bs[k][tx * 4];
      float avv[4] = {a4.x, a4.y, a4.z, a4.w};
      float bvv[4] = {b4.x, b4.y, b4.z, b4.w};
      #pragma unroll
      for (int i = 0; i < 4; ++i)
        #pragma unroll
        for (int j = 0; j < 4; ++j)
          acc[i][j] = fmaf(avv[i], bvv[j], acc[i][j]);
    }
  }
  float4 bi = *(const float4*)(bias + n0 + tx * 4);
  #pragma unroll
  for (int i = 0; i < 4; ++i) {
    int m = m0 + ty * 4 + i;
    size_t off = (size_t)m * N + n0 + tx * 4;
    float4 r;
    r.x = acc[i][0] + bi.x; r.y = acc[i][1] + bi.y;
    r.z = acc[i][2] + bi.z; r.w = acc[i][3] + bi.w;
    if (EPI == 1) {
      float4 rs = *(const float4*)(extra + off);
      r.x += rs.x; r.y += rs.y; r.z += rs.z; r.w += rs.w;
    }
    *(float4*)(C + off) = r;
  }
}

// ---------------- bucketed local attention via MFMA ---------------------------
// grid (nb=64, H=16, B=4), 256 thr = 4 waves; wave it owns q rows it*16..it*16+15.
// S = Q K^T (mfma), softmax in regs (+16-lane shfl), P ->LDS (A-layout), O = P V.
#define ATT_KP 72    // Kb row stride (elems): 64 + 8 pad, keeps 16B align
#define ATT_VP 136   // Vt/Pb row stride (elems): 128 + 8 pad
__global__ __launch_bounds__(256) void attn_mfma(const unsigned short* __restrict__ qkv,
    unsigned short* __restrict__ out)
{
  __shared__ __align__(16) unsigned short Kb[128 * ATT_KP];  // K rows [j][d]
  __shared__ __align__(16) unsigned short Vt[64 * ATT_VP];   // V^T [d][j]
  __shared__ __align__(16) unsigned short Pb[64 * ATT_VP];   // P [i][j] A-layout
  const int n = blockIdx.x, h = blockIdx.y, b = blockIdx.z;
  const int tid = threadIdx.x;
  const int wave = tid >> 6, lane = tid & 63;
  const int ln15 = lane & 15, quad = lane >> 4;
  const int C3 = 3 * CDIM;
  const size_t bbase = (size_t)b * T_SEQ * C3;
  const int kcol = CDIM + h * HDIM, vcol = 2 * CDIM + h * HDIM;

  // stage K[128][64]: rows 0..63 prev bucket (zeros if n==0), 64..127 current
  #pragma unroll
  for (int i = 0; i < 4; ++i) {
    int idx = tid + 256 * i;             // 1024 chunks of 8 elems
    int j = idx >> 3, d8 = (idx & 7) * 8;
    uint4 r = make_uint4(0u, 0u, 0u, 0u);
    if (j >= 64 || n > 0) {
      int t = (j >= 64) ? (n * BSZ + j - 64) : ((n - 1) * BSZ + j);
      r = *(const uint4*)(qkv + bbase + (size_t)t * C3 + kcol + d8);
    }
    *(uint4*)&Kb[j * ATT_KP + d8] = r;
  }
  // stage V transposed: Vt[d][j]
  #pragma unroll
  for (int i = 0; i < 16; ++i) {
    int idx = tid + 256 * i;             // 4096 d-pairs
    int j = idx >> 5, d2 = (idx & 31) * 2;
    unsigned int r = 0u;
    if (j >= 64 || n > 0) {
      int t = (j >= 64) ? (n * BSZ + j - 64) : ((n - 1) * BSZ + j);
      r = *(const unsigned int*)(qkv + bbase + (size_t)t * C3 + vcol + d2);
    }
    Vt[d2 * ATT_VP + j]       = (unsigned short)(r & 0xffffu);
    Vt[(d2 + 1) * ATT_VP + j] = (unsigned short)(r >> 16);
  }
  // Q fragments (A-operand) straight from global
  const int it = wave;
  const int qm = n * BSZ + it * 16 + ln15;
  bf16x8 aq[2];
  #pragma unroll
  for (int ks = 0; ks < 2; ++ks)
    aq[ks] = *(const bf16x8*)(qkv + bbase + (size_t)qm * C3 + h * HDIM + ks * 32 + quad * 8);
  __syncthreads();

  // S = Q K^T : 8 j-tiles, K=64 -> 2 mfma each
  f32x4 accs[8];
  #pragma unroll
  for (int jt = 0; jt < 8; ++jt) accs[jt] = (f32x4){0.f, 0.f, 0.f, 0.f};
  #pragma unroll
  for (int jt = 0; jt < 8; ++jt)
    #pragma unroll
    for (int ks = 0; ks < 2; ++ks) {
      bf16x8 bk = *(const bf16x8*)&Kb[(jt * 16 + ln15) * ATT_KP + ks * 32 + quad * 8];
      accs[jt] = __builtin_amdgcn_mfma_f32_16x16x32_bf16(aq[ks], bk, accs[jt], 0, 0, 0);
    }

  // mask + softmax per row irow = it*16 + quad*4 + r ; col j = jt*16 + ln15
  #pragma unroll
  for (int r = 0; r < 4; ++r) {
    const int irow = it * 16 + quad * 4 + r;
    float p8[8];
    float mx = -1e30f;
    #pragma unroll
    for (int jt = 0; jt < 8; ++jt) {
      int j = jt * 16 + ln15;
      float s = accs[jt][r] * 0.125f;
      bool ok = (j < BSZ) || (j - BSZ <= irow);
      s = ok ? s : -1e30f;
      p8[jt] = s;
      mx = fmaxf(mx, s);
    }
    mx = fmaxf(mx, __shfl_xor(mx, 1));
    mx = fmaxf(mx, __shfl_xor(mx, 2));
    mx = fmaxf(mx, __shfl_xor(mx, 4));
    mx = fmaxf(mx, __shfl_xor(mx, 8));
    float l = 0.f;
    #pragma unroll
    for (int jt = 0; jt < 8; ++jt) { float e = __expf(p8[jt] - mx); p8[jt] = e; l += e; }
    l += __shfl_xor(l, 1); l += __shfl_xor(l, 2);
    l += __shfl_xor(l, 4); l += __shfl_xor(l, 8);
    const float linv = 1.0f / l;
    #pragma unroll
    for (int jt = 0; jt < 8; ++jt)
      Pb[irow * ATT_VP + jt * 16 + ln15] = f2bf(p8[jt] * linv);
  }

  // O = P V : own-rows only -> within-wave LDS dep (compiler inserts lgkmcnt)
  f32x4 acco[4];
  #pragma unroll
  for (int dt = 0; dt < 4; ++dt) acco[dt] = (f32x4){0.f, 0.f, 0.f, 0.f};
  #pragma unroll
  for (int ks = 0; ks < 4; ++ks) {
    bf16x8 pa = *(const bf16x8*)&Pb[(it * 16 + ln15) * ATT_VP + ks * 32 + quad * 8];
    #pragma unroll
    for (int dt = 0; dt < 4; ++dt) {
      bf16x8 bv = *(const bf16x8*)&Vt[(dt * 16 + ln15) * ATT_VP + ks * 32 + quad * 8];
      acco[dt] = __builtin_amdgcn_mfma_f32_16x16x32_bf16(pa, bv, acco[dt], 0, 0, 0);
    }
  }

  unsigned short* op = out + (size_t)(b * T_SEQ + n * BSZ) * CDIM + h * HDIM;
  #pragma unroll
  for (int dt = 0; dt < 4; ++dt)
    #pragma unroll
    for (int r = 0; r < 4; ++r)
      op[(size_t)(it * 16 + quad * 4 + r) * CDIM + dt * 16 + ln15] = f2bf(acco[dt][r]);
}

// ---------------- critic head ------------------------------------------------
__global__ __launch_bounds__(256) void critic_kernel(const float* __restrict__ x,
    const float* __restrict__ w, const float* __restrict__ b, float* __restrict__ out)
{
  int row = blockIdx.x * 4 + (threadIdx.x >> 6);
  int lane = threadIdx.x & 63;
  const float* xr = x + (size_t)row * CDIM;
  float s = 0.f;
  #pragma unroll
  for (int i = 0; i < 16; ++i) s = fmaf(xr[lane + 64*i], w[lane + 64*i], s);
  #pragma unroll
  for (int o = 32; o > 0; o >>= 1) s += __shfl_down(s, o);
  if (lane == 0) out[row] = s + b[0];
}

__global__ void copy64_kernel(const float* __restrict__ in, float* __restrict__ out)
{
  out[threadIdx.x] = in[threadIdx.x];
}

// -----------------------------------------------------------------------------
extern "C" void kernel_launch(void* const* d_in, const int* in_sizes, int n_in,
                              void* d_out, int out_size, void* d_ws, size_t ws_size,
                              hipStream_t stream)
{
  const float* states   = (const float*)d_in[0];
  const float* emb_w    = (const float*)d_in[1];
  const float* emb_b    = (const float*)d_in[2];
  const float* pos      = (const float*)d_in[3];
  const float* ln1_w    = (const float*)d_in[4];
  const float* ln1_b    = (const float*)d_in[5];
  const float* qkv_w    = (const float*)d_in[6];
  const float* qkv_b    = (const float*)d_in[7];
  const float* ow       = (const float*)d_in[8];
  const float* obs      = (const float*)d_in[9];
  const float* ln2_w    = (const float*)d_in[10];
  const float* ln2_b    = (const float*)d_in[11];
  const float* w1       = (const float*)d_in[12];
  const float* b1       = (const float*)d_in[13];
  const float* w2       = (const float*)d_in[14];
  const float* b2       = (const float*)d_in[15];
  const float* lnf_w    = (const float*)d_in[16];
  const float* lnf_b    = (const float*)d_in[17];
  const float* actor_w  = (const float*)d_in[18];
  const float* actor_b  = (const float*)d_in[19];
  const float* logstd   = (const float*)d_in[20];
  const float* critic_w = (const float*)d_in[21];
  const float* critic_b = (const float*)d_in[22];

  char* wsb = (char*)d_ws;
  float* x              = (float*)wsb;
  unsigned short* qkvb  = (unsigned short*)(wsb + (64ull  << 20));
  float* hbuf           = (float*)(wsb + (64ull << 20));
  unsigned short* lnb   = (unsigned short*)(wsb + (160ull << 20));
  unsigned short* mlpb  = (unsigned short*)(wsb + (192ull << 20));
  unsigned short* statesb = mlpb;
  unsigned short* wq    = (unsigned short*)(wsb + (320ull << 20));
  unsigned short* wo    = wq  + (size_t)3072 * 1024;
  unsigned short* wm1   = wo  + (size_t)1024 * 1024;
  unsigned short* wm2   = wm1 + (size_t)4096 * 1024;
  unsigned short* wemb  = wm2 + (size_t)1024 * 4096;

  float* logits     = (float*)d_out;
  float* out_logstd = logits + (size_t)MROWS * 64;
  float* out_values = out_logstd + 64;

  dim3 blk(256);

  // embed: x = states@emb_w + emb_b + pos
  conv_flat<<<4096, blk, 0, stream>>>(states, statesb);
  convT<<<dim3(1024/32, 256/32), blk, 0, stream>>>(emb_w, wemb, 256, 1024);
  gemm_bf16<3,0><<<dim3(128 * 8), blk, 0, stream>>>(
      statesb, wemb, emb_b, pos, x, MROWS, CDIM, 256);

  for (int l = 0; l < NL; ++l) {
    convT<<<dim3(3072/32, 1024/32), blk, 0, stream>>>(qkv_w + (size_t)l*CDIM*3*CDIM, wq,  1024, 3072);
    convT<<<dim3(1024/32, 1024/32), blk, 0, stream>>>(ow    + (size_t)l*CDIM*CDIM,   wo,  1024, 1024);
    convT<<<dim3(4096/32, 1024/32), blk, 0, stream>>>(w1    + (size_t)l*CDIM*4*CDIM, wm1, 1024, 4096);
    convT<<<dim3(1024/32, 4096/32), blk, 0, stream>>>(w2    + (size_t)l*4*CDIM*CDIM, wm2, 4096, 1024);

    ln_kernel<1><<<MROWS, blk, 0, stream>>>(x, ln1_w + l*CDIM, ln1_b + l*CDIM, lnb);
    gemm_bf16<0,1><<<dim3(128 * 24), blk, 0, stream>>>(
        lnb, wq, qkv_b + (size_t)l*3*CDIM, nullptr, qkvb, MROWS, 3*CDIM, CDIM);
    attn_mfma<<<dim3(T_SEQ/BSZ, NH, 4), blk, 0, stream>>>(qkvb, lnb);
    gemm_bf16<1,0><<<dim3(128 * 8), blk, 0, stream>>>(
        lnb, wo, obs + (size_t)l*CDIM, x, x, MROWS, CDIM, CDIM);
    ln_kernel<1><<<MROWS, blk, 0, stream>>>(x, ln2_w + l*CDIM, ln2_b + l*CDIM, lnb);
    gemm_bf16<2,1><<<dim3(128 * 32), blk, 0, stream>>>(
        lnb, wm1, b1 + (size_t)l*4*CDIM, nullptr, mlpb, MROWS, 4*CDIM, CDIM);
    gemm_bf16<1,0><<<dim3(128 * 8), blk, 0, stream>>>(
        mlpb, wm2, b2 + (size_t)l*CDIM, x, x, MROWS, CDIM, 4*CDIM);
  }

  ln_kernel<0><<<MROWS, blk, 0, stream>>>(x, lnf_w, lnf_b, hbuf);
  gemm_f32<0><<<dim3(MROWS/64, 1), blk, 0, stream>>>(
      hbuf, actor_w, actor_b, nullptr, logits, MROWS, 64, CDIM);
  critic_kernel<<<MROWS/4, blk, 0, stream>>>(hbuf, critic_w, critic_b, out_values);
  copy64_kernel<<<1, 64, 0, stream>>>(logstd, out_logstd);
}

// Round 4
// 4609.676 us; speedup vs baseline: 7.8302x; 1.0869x over previous
//
#include <hip/hip_runtime.h>
#include <math.h>
#include <stdint.h>

#define T_SEQ 4096
#define CDIM  1024
#define NL    6
#define NH    16
#define BSZ   64
#define HDIM  64
#define MROWS 16384   // B*T

typedef __bf16 bf16x8 __attribute__((ext_vector_type(8)));
typedef float  f32x4  __attribute__((ext_vector_type(4)));

__device__ __forceinline__ unsigned short f2bf(float f) {
  __bf16 h = (__bf16)f;
  return __builtin_bit_cast(unsigned short, h);
}
__device__ __forceinline__ float bf2f(unsigned short u) {
  unsigned int v = ((unsigned int)u) << 16;
  return __builtin_bit_cast(float, v);
}

// async global->LDS, 16B per lane; lds dest must be wave-uniform (HW adds lane*16)
typedef __attribute__((address_space(3))) unsigned int* lds_u32p;
typedef const __attribute__((address_space(1))) unsigned int* glb_u32p;
__device__ __forceinline__ void glds16(const void* g, void* l) {
  __builtin_amdgcn_global_load_lds((glb_u32p)(uintptr_t)g, (lds_u32p)(uintptr_t)l, 16, 0, 0);
}

// Abramowitz-Stegun 7.1.26, |err| <= 1.5e-7 — invisible at bf16 precision
__device__ __forceinline__ float erf_fast(float x) {
  float ax = fabsf(x);
  float t = __builtin_amdgcn_rcpf(fmaf(0.3275911f, ax, 1.0f));
  float y = t * fmaf(t, fmaf(t, fmaf(t, fmaf(t, 1.061405429f, -1.453152027f),
                                     1.421413741f), -0.284496736f), 0.254829592f);
  float r = 1.0f - y * __expf(-ax * ax);
  return copysignf(r, x);
}
__device__ __forceinline__ float gelu_fast(float v) {
  return 0.5f * v * (1.0f + erf_fast(v * 0.70710678118654752440f));
}

// ---------------- LayerNorm: one block per row; OBF=1 -> bf16 out ------------
template<int OBF>
__global__ __launch_bounds__(256) void ln_kernel(const float* __restrict__ x,
    const float* __restrict__ w, const float* __restrict__ bb, void* __restrict__ out)
{
  int row = blockIdx.x;
  int tid = threadIdx.x;
  float4 v = ((const float4*)(x + (size_t)row * CDIM))[tid];
  float s  = v.x + v.y + v.z + v.w;
  float ss = v.x*v.x + v.y*v.y + v.z*v.z + v.w*v.w;
  #pragma unroll
  for (int o = 32; o > 0; o >>= 1) { s += __shfl_down(s, o); ss += __shfl_down(ss, o); }
  __shared__ float red[8];
  int wid = tid >> 6, lane = tid & 63;
  if (lane == 0) { red[wid] = s; red[4 + wid] = ss; }
  __syncthreads();
  if (tid == 0) {
    red[0] = red[0] + red[1] + red[2] + red[3];
    red[4] = red[4] + red[5] + red[6] + red[7];
  }
  __syncthreads();
  float mean = red[0] * (1.0f / CDIM);
  float var  = red[4] * (1.0f / CDIM) - mean * mean;
  float inv  = 1.0f / sqrtf(var + 1e-5f);
  float4 w4 = ((const float4*)w)[tid];
  float4 b4 = ((const float4*)bb)[tid];
  float4 o4;
  o4.x = (v.x - mean) * inv * w4.x + b4.x;
  o4.y = (v.y - mean) * inv * w4.y + b4.y;
  o4.z = (v.z - mean) * inv * w4.z + b4.z;
  o4.w = (v.w - mean) * inv * w4.w + b4.w;
  if (OBF) {
    ushort4 o;
    o.x = f2bf(o4.x); o.y = f2bf(o4.y); o.z = f2bf(o4.z); o.w = f2bf(o4.w);
    ((ushort4*)((unsigned short*)out + (size_t)row * CDIM))[tid] = o;
  } else {
    ((float4*)((float*)out + (size_t)row * CDIM))[tid] = o4;
  }
}

// ---------------- weight fp32 [K,N] -> bf16 W^T [N,K] ------------------------
__global__ __launch_bounds__(256) void convT(const float* __restrict__ W,
    unsigned short* __restrict__ Wt, int K, int N)
{
  __shared__ float tile[32][33];
  const int kt = blockIdx.y * 32, nt = blockIdx.x * 32;
  const int r = threadIdx.x >> 3;        // 0..31
  const int c = (threadIdx.x & 7) * 4;   // 0..28
  float4 v = *(const float4*)(W + (size_t)(kt + r) * N + nt + c);
  tile[r][c] = v.x; tile[r][c+1] = v.y; tile[r][c+2] = v.z; tile[r][c+3] = v.w;
  __syncthreads();
  ushort4 o;
  o.x = f2bf(tile[c+0][r]); o.y = f2bf(tile[c+1][r]);
  o.z = f2bf(tile[c+2][r]); o.w = f2bf(tile[c+3][r]);
  *(ushort4*)(Wt + (size_t)(nt + r) * K + kt + c) = o;
}

// ---------------- flat fp32 -> bf16 ------------------------------------------
__global__ void conv_flat(const float* __restrict__ in, unsigned short* __restrict__ out)
{
  int i = blockIdx.x * blockDim.x + threadIdx.x;
  float4 v = ((const float4*)in)[i];
  ushort4 o;
  o.x = f2bf(v.x); o.y = f2bf(v.y); o.z = f2bf(v.z); o.w = f2bf(v.w);
  ((ushort4*)out)[i] = o;
}

// ---------------- bf16 MFMA GEMM: C = A[M,K] @ B^T[N,K]^T --------------------
// 1D grid with 8-M-tile group swizzle for A reuse in L2/L3.
// EPI: 0=+bias ; 1=+bias+residual(extra f32) ; 2=gelu(+bias) ; 3=+bias+pos(extra)
// Epilogue repacks each wave's 16x64 sub-tiles through padded LDS so global
// stores are 16B-coalesced (no partial-line RMW); residual/pos adds happen in
// the read-back phase with coalesced float4 loads.
#define EPAD 68   // fp32 row stride in repack LDS (272 B: 16B-aligned, 2-way max)
template<int EPI, int OBF>
__global__ __launch_bounds__(256) void gemm_bf16(
    const unsigned short* __restrict__ A, const unsigned short* __restrict__ Bt,
    const float* __restrict__ bias, const float* __restrict__ extra,
    void* __restrict__ Cout, int M, int N, int K)
{
  __shared__ __align__(16) unsigned short As[128 * 32];  // [row][k] 64B rows
  __shared__ __align__(16) unsigned short Bs[128 * 32];  // [n][k]
  __shared__ __align__(16) float Ep[4 * 16 * EPAD];      // per-wave repack
  const int tid = threadIdx.x;
  const int wave = tid >> 6, lane = tid & 63;
  // swizzle: groups of 8 m-tiles sweep all n-tiles (A read ~once from HBM)
  const int ntiles = N >> 7;
  const int per = ntiles << 3;
  const int g = blockIdx.x / per, rr = blockIdx.x % per;
  const int m0 = ((g << 3) + (rr & 7)) << 7;
  const int n0 = (rr >> 3) << 7;
  const int wm = (wave & 1) * 64, wn = (wave >> 1) * 64;

  const int srow = wave * 32 + (lane >> 2);
  const int skq  = (lane & 3) * 8;
  const unsigned short* ag0 = A  + (size_t)(m0 + srow) * K + skq;
  const unsigned short* ag1 = ag0 + (size_t)16 * K;
  const unsigned short* bg0 = Bt + (size_t)(n0 + srow) * K + skq;
  const unsigned short* bg1 = bg0 + (size_t)16 * K;
  char* al0 = (char*)As + (wave * 32) * 64;
  char* al1 = al0 + 16 * 64;
  char* bl0 = (char*)Bs + (wave * 32) * 64;
  char* bl1 = bl0 + 16 * 64;

  const int fra = (wm + (lane & 15)) * 64 + (lane >> 4) * 16;
  const int frb = (wn + (lane & 15)) * 64 + (lane >> 4) * 16;

  f32x4 acc[4][4];
  #pragma unroll
  for (int i = 0; i < 4; ++i)
    #pragma unroll
    for (int j = 0; j < 4; ++j) acc[i][j] = (f32x4){0.f, 0.f, 0.f, 0.f};

  for (int k0 = 0; k0 < K; k0 += 32) {
    __syncthreads();
    glds16(ag0 + k0, al0);
    glds16(ag1 + k0, al1);
    glds16(bg0 + k0, bl0);
    glds16(bg1 + k0, bl1);
    __syncthreads();
    bf16x8 af[4], bfr[4];
    #pragma unroll
    for (int i = 0; i < 4; ++i) af[i] = *(const bf16x8*)((const char*)As + fra + i * 1024);
    #pragma unroll
    for (int j = 0; j < 4; ++j) bfr[j] = *(const bf16x8*)((const char*)Bs + frb + j * 1024);
    #pragma unroll
    for (int i = 0; i < 4; ++i)
      #pragma unroll
      for (int j = 0; j < 4; ++j)
        acc[i][j] = __builtin_amdgcn_mfma_f32_16x16x32_bf16(af[i], bfr[j], acc[i][j], 0, 0, 0);
  }

  // ---- epilogue via per-wave LDS repack (no barrier: within-wave deps) ----
  float* ep = Ep + wave * 16 * EPAD;
  const int cl = lane & 15, rq = (lane >> 4) * 4;
  #pragma unroll
  for (int i = 0; i < 4; ++i) {
    // write phase: bias (+gelu) applied, C/D layout col=cl, row=rq+r
    #pragma unroll
    for (int j = 0; j < 4; ++j) {
      const float bj = bias[n0 + wn + j * 16 + cl];
      #pragma unroll
      for (int r = 0; r < 4; ++r) {
        float val = acc[i][j][r] + bj;
        if (EPI == 2) val = gelu_fast(val);
        if (OBF) ((unsigned short*)ep)[(rq + r) * (2 * EPAD) + j * 16 + cl] = f2bf(val);
        else     ep[(rq + r) * EPAD + j * 16 + cl] = val;
      }
    }
    // read-back phase: row-major, coalesced 16B stores
    const int mbase = m0 + wm + i * 16;
    if (OBF) {
      #pragma unroll
      for (int s = 0; s < 2; ++s) {
        int f = s * 64 + lane;
        int row = f >> 3, ch = f & 7;
        uint4 v = *(const uint4*)((const unsigned short*)ep + row * (2 * EPAD) + ch * 8);
        *(uint4*)((unsigned short*)Cout + (size_t)(mbase + row) * N + n0 + wn + ch * 8) = v;
      }
    } else {
      #pragma unroll
      for (int s = 0; s < 4; ++s) {
        int f = s * 64 + lane;
        int row = f >> 4, ch = f & 15;
        float4 v = *(const float4*)(ep + row * EPAD + ch * 4);
        const int m = mbase + row;
        const size_t off = (size_t)m * N + n0 + wn + ch * 4;
        if (EPI == 1) {
          float4 e = *(const float4*)(extra + off);
          v.x += e.x; v.y += e.y; v.z += e.z; v.w += e.w;
        } else if (EPI == 3) {
          float4 e = *(const float4*)(extra + (size_t)(m & (T_SEQ - 1)) * N + n0 + wn + ch * 4);
          v.x += e.x; v.y += e.y; v.z += e.z; v.w += e.w;
        }
        *(float4*)((float*)Cout + off) = v;
      }
    }
  }
}

// ---------------- fp32 GEMM (kept for tiny actor head) -----------------------
template<int EPI>
__global__ __launch_bounds__(256) void gemm_f32(const float* __restrict__ A,
    const float* __restrict__ B, const float* __restrict__ bias,
    const float* __restrict__ extra, float* __restrict__ C,
    int M, int N, int K)
{
  __shared__ float As[16][64];
  __shared__ float Bs[16][64];
  const int tid = threadIdx.x;
  const int m0 = blockIdx.x * 64, n0 = blockIdx.y * 64;
  const int tx = tid & 15, ty = tid >> 4;
  const int ar = tid >> 2, ak = (tid & 3) * 4;
  const int br = tid >> 4, bc = (tid & 15) * 4;
  const float* Ap = A + (size_t)(m0 + ar) * K + ak;
  const float* Bp = B + (size_t)br * N + n0 + bc;
  float acc[4][4] = {};
  for (int k0 = 0; k0 < K; k0 += 16) {
    float4 av = *(const float4*)(Ap + k0);
    float4 bv = *(const float4*)(Bp + (size_t)k0 * N);
    __syncthreads();
    As[ak+0][ar] = av.x; As[ak+1][ar] = av.y; As[ak+2][ar] = av.z; As[ak+3][ar] = av.w;
    *(float4*)&Bs[br][bc] = bv;
    __syncthreads();
    #pragma unroll
    for (int k = 0; k < 16; ++k) {
      float4 a4 = *(const float4*)&As[k][ty * 4];
      float4 b4 = *(const float4*)&Bs[k][tx * 4];
      float avv[4] = {a4.x, a4.y, a4.z, a4.w};
      float bvv[4] = {b4.x, b4.y, b4.z, b4.w};
      #pragma unroll
      for (int i = 0; i < 4; ++i)
        #pragma unroll
        for (int j = 0; j < 4; ++j)
          acc[i][j] = fmaf(avv[i], bvv[j], acc[i][j]);
    }
  }
  float4 bi = *(const float4*)(bias + n0 + tx * 4);
  #pragma unroll
  for (int i = 0; i < 4; ++i) {
    int m = m0 + ty * 4 + i;
    size_t off = (size_t)m * N + n0 + tx * 4;
    float4 r;
    r.x = acc[i][0] + bi.x; r.y = acc[i][1] + bi.y;
    r.z = acc[i][2] + bi.z; r.w = acc[i][3] + bi.w;
    if (EPI == 1) {
      float4 rs = *(const float4*)(extra + off);
      r.x += rs.x; r.y += rs.y; r.z += rs.z; r.w += rs.w;
    }
    *(float4*)(C + off) = r;
  }
}

// ---------------- bucketed local attention via MFMA ---------------------------
#define ATT_KP 72    // Kb row stride (elems): 64 + 8 pad, keeps 16B align
#define ATT_VP 136   // Vt/Pb row stride (elems): 128 + 8 pad
__global__ __launch_bounds__(256) void attn_mfma(const unsigned short* __restrict__ qkv,
    unsigned short* __restrict__ out)
{
  __shared__ __align__(16) unsigned short Kb[128 * ATT_KP];  // K rows [j][d]
  __shared__ __align__(16) unsigned short Vt[64 * ATT_VP];   // V^T [d][j]
  __shared__ __align__(16) unsigned short Pb[64 * ATT_VP];   // P [i][j] A-layout
  const int n = blockIdx.x, h = blockIdx.y, b = blockIdx.z;
  const int tid = threadIdx.x;
  const int wave = tid >> 6, lane = tid & 63;
  const int ln15 = lane & 15, quad = lane >> 4;
  const int C3 = 3 * CDIM;
  const size_t bbase = (size_t)b * T_SEQ * C3;
  const int kcol = CDIM + h * HDIM, vcol = 2 * CDIM + h * HDIM;

  #pragma unroll
  for (int i = 0; i < 4; ++i) {
    int idx = tid + 256 * i;
    int j = idx >> 3, d8 = (idx & 7) * 8;
    uint4 r = make_uint4(0u, 0u, 0u, 0u);
    if (j >= 64 || n > 0) {
      int t = (j >= 64) ? (n * BSZ + j - 64) : ((n - 1) * BSZ + j);
      r = *(const uint4*)(qkv + bbase + (size_t)t * C3 + kcol + d8);
    }
    *(uint4*)&Kb[j * ATT_KP + d8] = r;
  }
  #pragma unroll
  for (int i = 0; i < 16; ++i) {
    int idx = tid + 256 * i;
    int j = idx >> 5, d2 = (idx & 31) * 2;
    unsigned int r = 0u;
    if (j >= 64 || n > 0) {
      int t = (j >= 64) ? (n * BSZ + j - 64) : ((n - 1) * BSZ + j);
      r = *(const unsigned int*)(qkv + bbase + (size_t)t * C3 + vcol + d2);
    }
    Vt[d2 * ATT_VP + j]       = (unsigned short)(r & 0xffffu);
    Vt[(d2 + 1) * ATT_VP + j] = (unsigned short)(r >> 16);
  }
  const int it = wave;
  const int qm = n * BSZ + it * 16 + ln15;
  bf16x8 aq[2];
  #pragma unroll
  for (int ks = 0; ks < 2; ++ks)
    aq[ks] = *(const bf16x8*)(qkv + bbase + (size_t)qm * C3 + h * HDIM + ks * 32 + quad * 8);
  __syncthreads();

  f32x4 accs[8];
  #pragma unroll
  for (int jt = 0; jt < 8; ++jt) accs[jt] = (f32x4){0.f, 0.f, 0.f, 0.f};
  #pragma unroll
  for (int jt = 0; jt < 8; ++jt)
    #pragma unroll
    for (int ks = 0; ks < 2; ++ks) {
      bf16x8 bk = *(const bf16x8*)&Kb[(jt * 16 + ln15) * ATT_KP + ks * 32 + quad * 8];
      accs[jt] = __builtin_amdgcn_mfma_f32_16x16x32_bf16(aq[ks], bk, accs[jt], 0, 0, 0);
    }

  #pragma unroll
  for (int r = 0; r < 4; ++r) {
    const int irow = it * 16 + quad * 4 + r;
    float p8[8];
    float mx = -1e30f;
    #pragma unroll
    for (int jt = 0; jt < 8; ++jt) {
      int j = jt * 16 + ln15;
      float s = accs[jt][r] * 0.125f;
      bool ok = (j < BSZ) || (j - BSZ <= irow);
      s = ok ? s : -1e30f;
      p8[jt] = s;
      mx = fmaxf(mx, s);
    }
    mx = fmaxf(mx, __shfl_xor(mx, 1));
    mx = fmaxf(mx, __shfl_xor(mx, 2));
    mx = fmaxf(mx, __shfl_xor(mx, 4));
    mx = fmaxf(mx, __shfl_xor(mx, 8));
    float l = 0.f;
    #pragma unroll
    for (int jt = 0; jt < 8; ++jt) { float e = __expf(p8[jt] - mx); p8[jt] = e; l += e; }
    l += __shfl_xor(l, 1); l += __shfl_xor(l, 2);
    l += __shfl_xor(l, 4); l += __shfl_xor(l, 8);
    const float linv = 1.0f / l;
    #pragma unroll
    for (int jt = 0; jt < 8; ++jt)
      Pb[irow * ATT_VP + jt * 16 + ln15] = f2bf(p8[jt] * linv);
  }

  f32x4 acco[4];
  #pragma unroll
  for (int dt = 0; dt < 4; ++dt) acco[dt] = (f32x4){0.f, 0.f, 0.f, 0.f};
  #pragma unroll
  for (int ks = 0; ks < 4; ++ks) {
    bf16x8 pa = *(const bf16x8*)&Pb[(it * 16 + ln15) * ATT_VP + ks * 32 + quad * 8];
    #pragma unroll
    for (int dt = 0; dt < 4; ++dt) {
      bf16x8 bv = *(const bf16x8*)&Vt[(dt * 16 + ln15) * ATT_VP + ks * 32 + quad * 8];
      acco[dt] = __builtin_amdgcn_mfma_f32_16x16x32_bf16(pa, bv, acco[dt], 0, 0, 0);
    }
  }

  unsigned short* op = out + (size_t)(b * T_SEQ + n * BSZ) * CDIM + h * HDIM;
  #pragma unroll
  for (int dt = 0; dt < 4; ++dt)
    #pragma unroll
    for (int r = 0; r < 4; ++r)
      op[(size_t)(it * 16 + quad * 4 + r) * CDIM + dt * 16 + ln15] = f2bf(acco[dt][r]);
}

// ---------------- critic head ------------------------------------------------
__global__ __launch_bounds__(256) void critic_kernel(const float* __restrict__ x,
    const float* __restrict__ w, const float* __restrict__ b, float* __restrict__ out)
{
  int row = blockIdx.x * 4 + (threadIdx.x >> 6);
  int lane = threadIdx.x & 63;
  const float* xr = x + (size_t)row * CDIM;
  float s = 0.f;
  #pragma unroll
  for (int i = 0; i < 16; ++i) s = fmaf(xr[lane + 64*i], w[lane + 64*i], s);
  #pragma unroll
  for (int o = 32; o > 0; o >>= 1) s += __shfl_down(s, o);
  if (lane == 0) out[row] = s + b[0];
}

__global__ void copy64_kernel(const float* __restrict__ in, float* __restrict__ out)
{
  out[threadIdx.x] = in[threadIdx.x];
}

// -----------------------------------------------------------------------------
extern "C" void kernel_launch(void* const* d_in, const int* in_sizes, int n_in,
                              void* d_out, int out_size, void* d_ws, size_t ws_size,
                              hipStream_t stream)
{
  const float* states   = (const float*)d_in[0];
  const float* emb_w    = (const float*)d_in[1];
  const float* emb_b    = (const float*)d_in[2];
  const float* pos      = (const float*)d_in[3];
  const float* ln1_w    = (const float*)d_in[4];
  const float* ln1_b    = (const float*)d_in[5];
  const float* qkv_w    = (const float*)d_in[6];
  const float* qkv_b    = (const float*)d_in[7];
  const float* ow       = (const float*)d_in[8];
  const float* obs      = (const float*)d_in[9];
  const float* ln2_w    = (const float*)d_in[10];
  const float* ln2_b    = (const float*)d_in[11];
  const float* w1       = (const float*)d_in[12];
  const float* b1       = (const float*)d_in[13];
  const float* w2       = (const float*)d_in[14];
  const float* b2       = (const float*)d_in[15];
  const float* lnf_w    = (const float*)d_in[16];
  const float* lnf_b    = (const float*)d_in[17];
  const float* actor_w  = (const float*)d_in[18];
  const float* actor_b  = (const float*)d_in[19];
  const float* logstd   = (const float*)d_in[20];
  const float* critic_w = (const float*)d_in[21];
  const float* critic_b = (const float*)d_in[22];

  char* wsb = (char*)d_ws;
  float* x              = (float*)wsb;
  unsigned short* qkvb  = (unsigned short*)(wsb + (64ull  << 20));
  float* hbuf           = (float*)(wsb + (64ull << 20));
  unsigned short* lnb   = (unsigned short*)(wsb + (160ull << 20));
  unsigned short* mlpb  = (unsigned short*)(wsb + (192ull << 20));
  unsigned short* statesb = mlpb;
  unsigned short* wq    = (unsigned short*)(wsb + (320ull << 20));
  unsigned short* wo    = wq  + (size_t)3072 * 1024;
  unsigned short* wm1   = wo  + (size_t)1024 * 1024;
  unsigned short* wm2   = wm1 + (size_t)4096 * 1024;
  unsigned short* wemb  = wm2 + (size_t)1024 * 4096;

  float* logits     = (float*)d_out;
  float* out_logstd = logits + (size_t)MROWS * 64;
  float* out_values = out_logstd + 64;

  dim3 blk(256);

  conv_flat<<<4096, blk, 0, stream>>>(states, statesb);
  convT<<<dim3(1024/32, 256/32), blk, 0, stream>>>(emb_w, wemb, 256, 1024);
  gemm_bf16<3,0><<<dim3(128 * 8), blk, 0, stream>>>(
      statesb, wemb, emb_b, pos, x, MROWS, CDIM, 256);

  for (int l = 0; l < NL; ++l) {
    convT<<<dim3(3072/32, 1024/32), blk, 0, stream>>>(qkv_w + (size_t)l*CDIM*3*CDIM, wq,  1024, 3072);
    convT<<<dim3(1024/32, 1024/32), blk, 0, stream>>>(ow    + (size_t)l*CDIM*CDIM,   wo,  1024, 1024);
    convT<<<dim3(4096/32, 1024/32), blk, 0, stream>>>(w1    + (size_t)l*CDIM*4*CDIM, wm1, 1024, 4096);
    convT<<<dim3(1024/32, 4096/32), blk, 0, stream>>>(w2    + (size_t)l*4*CDIM*CDIM, wm2, 4096, 1024);

    ln_kernel<1><<<MROWS, blk, 0, stream>>>(x, ln1_w + l*CDIM, ln1_b + l*CDIM, lnb);
    gemm_bf16<0,1><<<dim3(128 * 24), blk, 0, stream>>>(
        lnb, wq, qkv_b + (size_t)l*3*CDIM, nullptr, qkvb, MROWS, 3*CDIM, CDIM);
    attn_mfma<<<dim3(T_SEQ/BSZ, NH, 4), blk, 0, stream>>>(qkvb, lnb);
    gemm_bf16<1,0><<<dim3(128 * 8), blk, 0, stream>>>(
        lnb, wo, obs + (size_t)l*CDIM, x, x, MROWS, CDIM, CDIM);
    ln_kernel<1><<<MROWS, blk, 0, stream>>>(x, ln2_w + l*CDIM, ln2_b + l*CDIM, lnb);
    gemm_bf16<2,1><<<dim3(128 * 32), blk, 0, stream>>>(
        lnb, wm1, b1 + (size_t)l*4*CDIM, nullptr, mlpb, MROWS, 4*CDIM, CDIM);
    gemm_bf16<1,0><<<dim3(128 * 8), blk, 0, stream>>>(
        mlpb, wm2, b2 + (size_t)l*CDIM, x, x, MROWS, CDIM, 4*CDIM);
  }

  ln_kernel<0><<<MROWS, blk, 0, stream>>>(x, lnf_w, lnf_b, hbuf);
  gemm_f32<0><<<dim3(MROWS/64, 1), blk, 0, stream>>>(
      hbuf, actor_w, actor_b, nullptr, logits, MROWS, 64, CDIM);
  critic_kernel<<<MROWS/4, blk, 0, stream>>>(hbuf, critic_w, critic_b, out_values);
  copy64_kernel<<<1, 64, 0, stream>>>(logstd, out_logstd);
}